// Round 8
// baseline (664.098 us; speedup 1.0000x reference)
//
#include <hip/hip_runtime.h>
#include <float.h>

#define K_CLUST 10000
#define K_PAD   10240           // 640 k-tiles of 16
#define DIM     128
#define N_SAMP  16384
#define KSPLIT  16
#define KT_PER  40              // 640 ktiles / 16 splits
#define MARGIN2 1.5f            // 2x worst-case f16 score error (validated r4-r7)

typedef _Float16 half8  __attribute__((ext_vector_type(8)));
typedef float    floatx4 __attribute__((ext_vector_type(4)));
typedef unsigned long long u64;

// order-preserving float<->uint encoding
__device__ inline unsigned enc_f(float f) {
    unsigned u = __float_as_uint(f);
    return u ^ (((int)u >> 31) | 0x80000000u);
}
__device__ inline float dec_f(unsigned u) {
    unsigned t = (u & 0x80000000u) ? (u ^ 0x80000000u) : ~u;
    return __uint_as_float(t);
}

// ---- Kernel 1: prep. blocks [0,320): m-side, 32 k each. [320,576): x-side, 64 samples.
__global__ __launch_bounds__(256) void prep_kernel(
        const float* __restrict__ m, const float* __restrict__ x,
        float* __restrict__ msq, float* __restrict__ mT,
        _Float16* __restrict__ mh, _Float16* __restrict__ xh,
        int* __restrict__ amb_cnt, float* __restrict__ diff_out) {
    const int b = blockIdx.x, tid = threadIdx.x;

    if (b < 320) {                              // ---- m part: k0 = b*32
        __shared__ float tile[32][DIM + 1];
        __shared__ float psum[32][8];
        const int k0 = b * 32;
        const int kl = tid & 31, dg = tid >> 5;  // 8 d-groups x 16 d
        const int k = k0 + kl;
        float ss = 0.f;
        #pragma unroll 4
        for (int dd = 0; dd < 16; ++dd) {
            int d = dg * 16 + dd;
            float v = (k < K_CLUST) ? m[(size_t)d * K_CLUST + k] : 0.f;
            tile[kl][d] = v;
            ss = fmaf(v, v, ss);
        }
        psum[kl][dg] = ss;
        __syncthreads();
        if (dg == 0) {
            float t = 0.f;
            #pragma unroll
            for (int g = 0; g < 8; ++g) t += psum[kl][g];
            msq[k] = (k < K_CLUST) ? t : -1e30f;    // pad never wins
        }
        // mh: [k/16][d/8][k%16][d%8] f16; 2 k-tiles per block
        #pragma unroll
        for (int p = 0; p < 2; ++p) {
            int c = tid + p * 256;              // 0..511
            int kt = c >> 8, dgc = (c >> 4) & 15, k16 = c & 15;
            half8 hv;
            #pragma unroll
            for (int j = 0; j < 8; ++j) hv[j] = (_Float16)tile[kt * 16 + k16][dgc * 8 + j];
            size_t ci = ((size_t)(b * 2 + kt) * 16 + dgc) * 16 + k16;
            ((half8*)mh)[ci] = hv;
        }
        // mT [K,DIM] fp32 for quant gather
        const int r = tid >> 3, p2 = tid & 7;
        if (k0 + r < K_CLUST) {
            float4* dst = (float4*)(mT + (size_t)(k0 + r) * DIM + p2 * 16);
            #pragma unroll
            for (int j = 0; j < 4; ++j) {
                float4 v;
                v.x = tile[r][p2 * 16 + 4 * j + 0];
                v.y = tile[r][p2 * 16 + 4 * j + 1];
                v.z = tile[r][p2 * 16 + 4 * j + 2];
                v.w = tile[r][p2 * 16 + 4 * j + 3];
                dst[j] = v;
            }
        }
    } else {                                    // ---- x part: s0 = (b-320)*64
        __shared__ float tile[64][DIM + 1];
        const int s0 = (b - 320) * 64;
        const float4* xg = (const float4*)(x + (size_t)s0 * DIM);
        #pragma unroll
        for (int i = 0; i < 8; ++i) {
            int fi = tid + i * 256;             // 0..2047
            int sl = fi >> 5, d4 = fi & 31;
            float4 v = xg[fi];
            tile[sl][d4 * 4 + 0] = v.x; tile[sl][d4 * 4 + 1] = v.y;
            tile[sl][d4 * 4 + 2] = v.z; tile[sl][d4 * 4 + 3] = v.w;
        }
        __syncthreads();
        // xh: [s/16][d/8][s%16][d%8]
        #pragma unroll
        for (int p = 0; p < 4; ++p) {
            int c = tid + p * 256;
            int st = c >> 8, dgc = (c >> 4) & 15, ml = c & 15;
            half8 hv;
            #pragma unroll
            for (int j = 0; j < 8; ++j) hv[j] = (_Float16)tile[st * 16 + ml][dgc * 8 + j];
            size_t ci = ((size_t)(s0 / 16 + st) * 16 + dgc) * 16 + ml;
            ((half8*)xh)[ci] = hv;
        }
        if (b == 320 && tid == 0) { *diff_out = 0.f; *amb_cnt = 0; }
    }
}

// ---- Kernel 2: SINGLE f16 MFMA pass. Per (sample, split): best score+argmax (packed
// u64) and 2nd-best score. r6's 4-tile shape (best measured: 58 us/pass).
// __launch_bounds__(256,3): 170-reg budget fits the ~150-reg live set (r5 lesson:
// never budget below the resident tile; r6/r7: occupancy pins at ~3 waves/SIMD anyway).
__global__ __launch_bounds__(256, 3) void score_kernel(
        const _Float16* __restrict__ xh, const _Float16* __restrict__ mh,
        const float* __restrict__ msq, u64* __restrict__ bpack,
        float* __restrict__ b2nd) {
    const int tid = threadIdx.x;
    const int wv = tid >> 6, lane = tid & 63;
    const int n = lane & 15, quad = lane >> 4;
    const int ks = blockIdx.x & (KSPLIT - 1);
    const int grp = blockIdx.x / KSPLIT;        // 64 groups x 256 samples
    const int stile0 = (grp * 4 + wv) * 4;      // 4 sample-tiles per wave
    const int kt0 = ks * KT_PER;

    const half8* xf = (const half8*)xh;
    const half8* mf = (const half8*)mh;

    half8 a[4][4];                              // 64 VGPRs resident
    #pragma unroll
    for (int ii = 0; ii < 4; ++ii)
        #pragma unroll
        for (int t = 0; t < 4; ++t)
            a[ii][t] = xf[((size_t)(stile0 + ii) * 16 + t * 4 + quad) * 16 + n];

    float b1[4][4], b2[4][4];
    int   k1[4][4];
    #pragma unroll
    for (int ii = 0; ii < 4; ++ii)
        #pragma unroll
        for (int r = 0; r < 4; ++r) {
            b1[ii][r] = -FLT_MAX; b2[ii][r] = -FLT_MAX; k1[ii][r] = 0;
        }

    for (int kt = kt0; kt < kt0 + KT_PER; ++kt) {
        half8 bfr[4];
        #pragma unroll
        for (int t = 0; t < 4; ++t)
            bfr[t] = mf[((size_t)kt * 16 + t * 4 + quad) * 16 + n];
        float mq = msq[kt * 16 + n];
        int kcur = kt * 16 + n;
        #pragma unroll
        for (int ii = 0; ii < 4; ++ii) {
            floatx4 c = {0.f, 0.f, 0.f, 0.f};
            #pragma unroll
            for (int t = 0; t < 4; ++t)
                c = __builtin_amdgcn_mfma_f32_16x16x32_f16(a[ii][t], bfr[t], c, 0, 0, 0);
            #pragma unroll
            for (int r = 0; r < 4; ++r) {
                float sc = fmaf(-2.f, c[r], mq);
                // best/2nd/argmax: b2 <- med3(b1,b2,sc); (b1,k1) <- max
                b2[ii][r] = fmaxf(b2[ii][r], fminf(sc, b1[ii][r]));
                bool gt = sc > b1[ii][r];
                b1[ii][r] = gt ? sc : b1[ii][r];
                k1[ii][r] = gt ? kcur : k1[ii][r];
            }
        }
    }

    // reduce over the 16 n-lanes of each quad
    #pragma unroll
    for (int ii = 0; ii < 4; ++ii)
        #pragma unroll
        for (int r = 0; r < 4; ++r) {
            float v1 = b1[ii][r], v2 = b2[ii][r];
            int   kk = k1[ii][r];
            #pragma unroll
            for (int mk = 1; mk <= 8; mk <<= 1) {
                float o1 = __shfl_xor(v1, mk);
                int   ok = __shfl_xor(kk, mk);
                float o2 = __shfl_xor(v2, mk);
                v2 = fmaxf(fmaxf(v2, o2), fminf(v1, o1));
                if (o1 > v1 || (o1 == v1 && ok < kk)) { v1 = o1; kk = ok; }
            }
            if (n == 0) {
                int sample = (stile0 + ii) * 16 + quad * 4 + r;
                bpack[(size_t)ks * N_SAMP + sample] =
                    ((u64)enc_f(v1) << 32) | (unsigned)(0xFFFFFFFFu - kk);
                b2nd[(size_t)ks * N_SAMP + sample] = v2;
            }
        }
}

// ---- Kernel 3: merge splits; decide final idx or flag ambiguous.
__global__ __launch_bounds__(256) void merge_kernel(
        const u64* __restrict__ bpack, const float* __restrict__ b2nd,
        int* __restrict__ idx_i, u64* __restrict__ rpack,
        int* __restrict__ amb, int* __restrict__ amb_cnt) {
    int s = blockIdx.x * 256 + threadIdx.x;
    u64 p1 = 0, p2 = 0;
    float m2 = -FLT_MAX;
    #pragma unroll
    for (int i = 0; i < KSPLIT; ++i) {
        u64 p = bpack[(size_t)i * N_SAMP + s];
        m2 = fmaxf(m2, b2nd[(size_t)i * N_SAMP + s]);
        if (p > p1) { p2 = p1; p1 = p; }
        else if (p > p2) p2 = p;
    }
    float f1 = dec_f((unsigned)(p1 >> 32));
    float f2 = fmaxf(m2, dec_f((unsigned)(p2 >> 32)));
    int k = (int)(0xFFFFFFFFu - (unsigned)(p1 & 0xFFFFFFFFu));
    if (f1 - f2 > MARGIN2) {
        idx_i[s] = k;                       // f16 argmax provably == fp32 argmax
    } else {
        idx_i[s] = -1;
        rpack[s] = 0;                       // any valid enc > 0
        int pos = atomicAdd(amb_cnt, 1);
        amb[pos] = s;
    }
}

// ---- Kernel 4: exact fp32 rescue for ambiguous samples. Work-item =
// (sample, 1/16th of K); one wave per item, lane-parallel over k (m layout coalesced).
__global__ __launch_bounds__(256) void rescue_kernel(
        const float* __restrict__ x, const float* __restrict__ m,
        const float* __restrict__ msq, const int* __restrict__ amb,
        const int* __restrict__ amb_cnt, u64* __restrict__ rpack) {
    const int wv = threadIdx.x >> 6, lane = threadIdx.x & 63;
    const int w = blockIdx.x * 4 + wv;          // 4096 waves
    const int total = (*amb_cnt) * 16;
    for (int item = w; item < total; item += 4096) {
        const int s  = amb[item >> 4];
        const int kb = (item & 15) * 640;
        float acc[10];
        #pragma unroll
        for (int i = 0; i < 10; ++i) acc[i] = 0.f;
        for (int d = 0; d < DIM; ++d) {
            float xv = x[(size_t)s * DIM + d];          // wave-uniform -> scalar
            const float* mrow = m + (size_t)d * K_CLUST;
            #pragma unroll
            for (int i = 0; i < 10; ++i) {
                int k = kb + i * 64 + lane;
                acc[i] = fmaf(xv, mrow[min(k, K_CLUST - 1)], acc[i]);
            }
        }
        float best = -FLT_MAX; int bk = 0;
        #pragma unroll
        for (int i = 0; i < 10; ++i) {
            int k = kb + i * 64 + lane;
            float sc = (k < K_CLUST) ? (msq[k] - 2.f * acc[i]) : -FLT_MAX;
            if (sc > best) { best = sc; bk = k; }       // ascending k: keeps lowest
        }
        u64 pk = ((u64)enc_f(best) << 32) | (unsigned)(0xFFFFFFFFu - bk);
        #pragma unroll
        for (int off = 32; off; off >>= 1) {
            u64 o = __shfl_xor((unsigned long long)pk, off);
            pk = (o > pk) ? o : pk;
        }
        if (lane == 0) atomicMax(&rpack[s], pk);
    }
}

// ---- Kernel 5: gather quantize (coalesced via mT), write index, MSE.
__global__ void quant_kernel(const float* __restrict__ x, const float* __restrict__ mT,
                             const int* __restrict__ idx_i, const u64* __restrict__ rpack,
                             float* __restrict__ qout, float* __restrict__ idx_f,
                             float* __restrict__ diff_out) {
    int g = blockIdx.x * 256 + threadIdx.x;     // one thread per (sample, d4)
    int samp = g >> 5;
    int d4   = g & 31;
    int idx  = idx_i[samp];
    if (idx < 0) idx = (int)(0xFFFFFFFFu - (unsigned)(rpack[samp] & 0xFFFFFFFFu));
    float4 q  = ((const float4*)mT)[(size_t)idx * (DIM / 4) + d4];
    float4 xv = ((const float4*)x)[g];
    ((float4*)qout)[g] = q;
    if (d4 == 0) idx_f[samp] = (float)idx;
    float ax = xv.x - q.x, ay = xv.y - q.y, az = xv.z - q.z, aw = xv.w - q.w;
    float dd = ax * ax + ay * ay + az * az + aw * aw;
    #pragma unroll
    for (int off = 32; off; off >>= 1) dd += __shfl_down(dd, off);
    __shared__ float wsum[4];
    int lane = threadIdx.x & 63, wv = threadIdx.x >> 6;
    if (lane == 0) wsum[wv] = dd;
    __syncthreads();
    if (threadIdx.x == 0) {
        float t = wsum[0] + wsum[1] + wsum[2] + wsum[3];
        atomicAdd(diff_out, t * (1.0f / ((float)N_SAMP * (float)DIM)));
    }
}

extern "C" void kernel_launch(void* const* d_in, const int* in_sizes, int n_in,
                              void* d_out, int out_size, void* d_ws, size_t ws_size,
                              hipStream_t stream) {
    const float* x = (const float*)d_in[0];          // [16,32,32,128]
    const float* m = (const float*)d_in[1];          // [128,10000]
    float* out    = (float*)d_out;
    float* quant  = out;                                  // 2,097,152 f
    float* idx_f  = out + (size_t)N_SAMP * DIM;           // 16,384 f
    float* diff   = out + (size_t)N_SAMP * DIM + N_SAMP;  // 1 f

    char* ws = (char*)d_ws;                  // ~15.4 MB total
    float*     msq   = (float*)    (ws);                      // 10240 f
    float*     mT    = (float*)    (ws + 40960);              // 5,120,000 B
    _Float16*  mh    = (_Float16*) (ws + 5160960);            // 2,621,440 B
    _Float16*  xh    = (_Float16*) (ws + 7782400);            // 4,194,304 B
    u64*       bpack = (u64*)      (ws + 11976704);           // 16*16384*8 = 2 MB
    float*     b2nd  = (float*)    (ws + 14073856);           // 16*16384*4 = 1 MB
    int*       idx_i = (int*)      (ws + 15122432);           // 64 KB
    u64*       rpack = (u64*)      (ws + 15187968);           // 128 KB
    int*       amb   = (int*)      (ws + 15319040);           // 64 KB
    int*       amb_c = (int*)      (ws + 15384576);           // 4 B

    prep_kernel<<<576, 256, 0, stream>>>(m, x, msq, mT, mh, xh, amb_c, diff);
    score_kernel<<<64 * KSPLIT, 256, 0, stream>>>(xh, mh, msq, bpack, b2nd);
    merge_kernel<<<N_SAMP / 256, 256, 0, stream>>>(bpack, b2nd, idx_i, rpack, amb, amb_c);
    rescue_kernel<<<1024, 256, 0, stream>>>(x, m, msq, amb, amb_c, rpack);
    quant_kernel<<<(N_SAMP * DIM / 4) / 256, 256, 0, stream>>>(x, mT, idx_i, rpack,
                                                               quant, idx_f, diff);
}

// Round 9
// 212.405 us; speedup vs baseline: 3.1266x; 3.1266x over previous
//
#include <hip/hip_runtime.h>
#include <float.h>

#define K_CLUST 10000
#define K_PAD   10240           // 640 k-tiles of 16
#define DIM     128
#define N_SAMP  16384
#define KSPLIT  16
#define KT_PER  40              // 640 ktiles / 16 splits
#define CAP     16              // candidate slots per ambiguous sample
#define MARGIN2 1.5f            // 2x worst-case f16 score error (validated r4-r8)

typedef _Float16 half8  __attribute__((ext_vector_type(8)));
typedef float    floatx4 __attribute__((ext_vector_type(4)));
typedef unsigned long long u64;

// order-preserving float<->uint encoding
__device__ inline unsigned enc_f(float f) {
    unsigned u = __float_as_uint(f);
    return u ^ (((int)u >> 31) | 0x80000000u);
}
__device__ inline float dec_f(unsigned u) {
    unsigned t = (u & 0x80000000u) ? (u ^ 0x80000000u) : ~u;
    return __uint_as_float(t);
}

// ---- Kernel 1: prep. blocks [0,320): m-side, 32 k each. [320,576): x-side, 64 samples.
__global__ __launch_bounds__(256) void prep_kernel(
        const float* __restrict__ m, const float* __restrict__ x,
        float* __restrict__ msq, float* __restrict__ mT,
        _Float16* __restrict__ mh, _Float16* __restrict__ xh,
        int* __restrict__ amb_cnt, float* __restrict__ diff_out) {
    const int b = blockIdx.x, tid = threadIdx.x;

    if (b < 320) {                              // ---- m part: k0 = b*32
        __shared__ float tile[32][DIM + 1];
        __shared__ float psum[32][8];
        const int k0 = b * 32;
        const int kl = tid & 31, dg = tid >> 5;  // 8 d-groups x 16 d
        const int k = k0 + kl;
        float ss = 0.f;
        #pragma unroll 4
        for (int dd = 0; dd < 16; ++dd) {
            int d = dg * 16 + dd;
            float v = (k < K_CLUST) ? m[(size_t)d * K_CLUST + k] : 0.f;
            tile[kl][d] = v;
            ss = fmaf(v, v, ss);
        }
        psum[kl][dg] = ss;
        __syncthreads();
        if (dg == 0) {
            float t = 0.f;
            #pragma unroll
            for (int g = 0; g < 8; ++g) t += psum[kl][g];
            msq[k] = (k < K_CLUST) ? t : -1e30f;    // pad never wins
        }
        // mh: [k/16][d/8][k%16][d%8] f16; 2 k-tiles per block
        #pragma unroll
        for (int p = 0; p < 2; ++p) {
            int c = tid + p * 256;              // 0..511
            int kt = c >> 8, dgc = (c >> 4) & 15, k16 = c & 15;
            half8 hv;
            #pragma unroll
            for (int j = 0; j < 8; ++j) hv[j] = (_Float16)tile[kt * 16 + k16][dgc * 8 + j];
            size_t ci = ((size_t)(b * 2 + kt) * 16 + dgc) * 16 + k16;
            ((half8*)mh)[ci] = hv;
        }
        // mT [K,DIM] fp32 for rescue/quant gather
        const int r = tid >> 3, p2 = tid & 7;
        if (k0 + r < K_CLUST) {
            float4* dst = (float4*)(mT + (size_t)(k0 + r) * DIM + p2 * 16);
            #pragma unroll
            for (int j = 0; j < 4; ++j) {
                float4 v;
                v.x = tile[r][p2 * 16 + 4 * j + 0];
                v.y = tile[r][p2 * 16 + 4 * j + 1];
                v.z = tile[r][p2 * 16 + 4 * j + 2];
                v.w = tile[r][p2 * 16 + 4 * j + 3];
                dst[j] = v;
            }
        }
    } else {                                    // ---- x part: s0 = (b-320)*64
        __shared__ float tile[64][DIM + 1];
        const int s0 = (b - 320) * 64;
        const float4* xg = (const float4*)(x + (size_t)s0 * DIM);
        #pragma unroll
        for (int i = 0; i < 8; ++i) {
            int fi = tid + i * 256;             // 0..2047
            int sl = fi >> 5, d4 = fi & 31;
            float4 v = xg[fi];
            tile[sl][d4 * 4 + 0] = v.x; tile[sl][d4 * 4 + 1] = v.y;
            tile[sl][d4 * 4 + 2] = v.z; tile[sl][d4 * 4 + 3] = v.w;
        }
        __syncthreads();
        // xh: [s/16][d/8][s%16][d%8]
        #pragma unroll
        for (int p = 0; p < 4; ++p) {
            int c = tid + p * 256;
            int st = c >> 8, dgc = (c >> 4) & 15, ml = c & 15;
            half8 hv;
            #pragma unroll
            for (int j = 0; j < 8; ++j) hv[j] = (_Float16)tile[st * 16 + ml][dgc * 8 + j];
            size_t ci = ((size_t)(s0 / 16 + st) * 16 + dgc) * 16 + ml;
            ((half8*)xh)[ci] = hv;
        }
        if (b == 320 && tid == 0) { *diff_out = 0.f; *amb_cnt = 0; }
    }
}

// ---- Kernel 2: SINGLE f16 MFMA pass. Per (sample, split): best score+argmax (packed
// u64) and 2nd-best score. r6's 4-tile shape. (256,3): 170-reg budget fits ~150 live.
__global__ __launch_bounds__(256, 3) void score_kernel(
        const _Float16* __restrict__ xh, const _Float16* __restrict__ mh,
        const float* __restrict__ msq, u64* __restrict__ bpack,
        float* __restrict__ b2nd) {
    const int tid = threadIdx.x;
    const int wv = tid >> 6, lane = tid & 63;
    const int n = lane & 15, quad = lane >> 4;
    const int ks = blockIdx.x & (KSPLIT - 1);
    const int grp = blockIdx.x / KSPLIT;        // 64 groups x 256 samples
    const int stile0 = (grp * 4 + wv) * 4;      // 4 sample-tiles per wave
    const int kt0 = ks * KT_PER;

    const half8* xf = (const half8*)xh;
    const half8* mf = (const half8*)mh;

    half8 a[4][4];                              // 64 VGPRs resident
    #pragma unroll
    for (int ii = 0; ii < 4; ++ii)
        #pragma unroll
        for (int t = 0; t < 4; ++t)
            a[ii][t] = xf[((size_t)(stile0 + ii) * 16 + t * 4 + quad) * 16 + n];

    float b1[4][4], b2[4][4];
    int   k1[4][4];
    #pragma unroll
    for (int ii = 0; ii < 4; ++ii)
        #pragma unroll
        for (int r = 0; r < 4; ++r) {
            b1[ii][r] = -FLT_MAX; b2[ii][r] = -FLT_MAX; k1[ii][r] = 0;
        }

    for (int kt = kt0; kt < kt0 + KT_PER; ++kt) {
        half8 bfr[4];
        #pragma unroll
        for (int t = 0; t < 4; ++t)
            bfr[t] = mf[((size_t)kt * 16 + t * 4 + quad) * 16 + n];
        float mq = msq[kt * 16 + n];
        int kcur = kt * 16 + n;
        #pragma unroll
        for (int ii = 0; ii < 4; ++ii) {
            floatx4 c = {0.f, 0.f, 0.f, 0.f};
            #pragma unroll
            for (int t = 0; t < 4; ++t)
                c = __builtin_amdgcn_mfma_f32_16x16x32_f16(a[ii][t], bfr[t], c, 0, 0, 0);
            #pragma unroll
            for (int r = 0; r < 4; ++r) {
                float sc = fmaf(-2.f, c[r], mq);
                b2[ii][r] = fmaxf(b2[ii][r], fminf(sc, b1[ii][r]));  // med3 given b2<=b1
                bool gt = sc > b1[ii][r];
                b1[ii][r] = gt ? sc : b1[ii][r];
                k1[ii][r] = gt ? kcur : k1[ii][r];
            }
        }
    }

    // reduce over the 16 n-lanes of each quad
    #pragma unroll
    for (int ii = 0; ii < 4; ++ii)
        #pragma unroll
        for (int r = 0; r < 4; ++r) {
            float v1 = b1[ii][r], v2 = b2[ii][r];
            int   kk = k1[ii][r];
            #pragma unroll
            for (int mk = 1; mk <= 8; mk <<= 1) {
                float o1 = __shfl_xor(v1, mk);
                int   ok = __shfl_xor(kk, mk);
                float o2 = __shfl_xor(v2, mk);
                v2 = fmaxf(fmaxf(v2, o2), fminf(v1, o1));
                if (o1 > v1 || (o1 == v1 && ok < kk)) { v1 = o1; kk = ok; }
            }
            if (n == 0) {
                int sample = (stile0 + ii) * 16 + quad * 4 + r;
                bpack[(size_t)ks * N_SAMP + sample] =
                    ((u64)enc_f(v1) << 32) | (unsigned)(0xFFFFFFFFu - kk);
                b2nd[(size_t)ks * N_SAMP + sample] = v2;
            }
        }
}

// ---- Kernel 3: merge splits; final idx if gap > MARGIN2, else append to compacted
// ambiguous list with per-sample collect threshold.
__global__ __launch_bounds__(256) void merge_kernel(
        const u64* __restrict__ bpack, const float* __restrict__ b2nd,
        int* __restrict__ idx_i, int* __restrict__ amb, float* __restrict__ thr_buf,
        int* __restrict__ cnt, int* __restrict__ amb_cnt) {
    int s = blockIdx.x * 256 + threadIdx.x;
    u64 p1 = 0, p2 = 0;
    float m2 = -FLT_MAX;
    #pragma unroll
    for (int i = 0; i < KSPLIT; ++i) {
        u64 p = bpack[(size_t)i * N_SAMP + s];
        m2 = fmaxf(m2, b2nd[(size_t)i * N_SAMP + s]);
        if (p > p1) { p2 = p1; p1 = p; }
        else if (p > p2) p2 = p;
    }
    float f1 = dec_f((unsigned)(p1 >> 32));
    float f2 = fmaxf(m2, dec_f((unsigned)(p2 >> 32)));
    int k = (int)(0xFFFFFFFFu - (unsigned)(p1 & 0xFFFFFFFFu));
    if (f1 - f2 > MARGIN2) {
        idx_i[s] = k;                       // f16 argmax provably == fp32 argmax
    } else {
        idx_i[s] = -1;
        cnt[s] = 0;
        int pos = atomicAdd(amb_cnt, 1);
        amb[pos] = s;
        thr_buf[pos] = f1 - MARGIN2;        // k* has sc16 >= f1 - 2E (bit-identical MFMA)
    }
}

// ---- Kernel 4: compacted COLLECT pass -- MFMA only over ambiguous sample-tiles.
// Work-item = (compacted-tile, ks). A-frags gathered per-lane via amb[] indirection.
__global__ __launch_bounds__(256) void collect_kernel(
        const _Float16* __restrict__ xh, const _Float16* __restrict__ mh,
        const float* __restrict__ msq, const int* __restrict__ amb,
        const float* __restrict__ thr_buf, const int* __restrict__ amb_cnt,
        int* __restrict__ cnt, int* __restrict__ cand) {
    const int wv = threadIdx.x >> 6, lane = threadIdx.x & 63;
    const int n = lane & 15, quad = lane >> 4;
    const int na = *amb_cnt;
    if (na == 0) return;
    const int total = ((na + 15) >> 4) * KSPLIT;
    const half8* xf = (const half8*)xh;
    const half8* mf = (const half8*)mh;

    for (int item = blockIdx.x * 4 + wv; item < total; item += gridDim.x * 4) {
        const int ctile = item / KSPLIT;
        const int ks = item - ctile * KSPLIT;
        // gather A-frags: MFMA A row m = lane&15 -> compacted sample amb[ctile*16+n]
        const int sn = amb[min(ctile * 16 + n, na - 1)];
        half8 a[4];
        #pragma unroll
        for (int t = 0; t < 4; ++t)
            a[t] = xf[((size_t)(sn >> 4) * 16 + t * 4 + quad) * 16 + (sn & 15)];
        // C rows quad*4+r -> compacted positions ctile*16+quad*4+r
        float thr[4]; int rs[4];
        #pragma unroll
        for (int r = 0; r < 4; ++r) {
            int pos = ctile * 16 + quad * 4 + r;
            bool ok = pos < na;
            rs[r]  = amb[ok ? pos : 0];
            thr[r] = ok ? thr_buf[pos] : 3.0e38f;   // padded rows never collect
        }
        for (int kt = ks * KT_PER; kt < (ks + 1) * KT_PER; ++kt) {
            half8 bfr[4];
            #pragma unroll
            for (int t = 0; t < 4; ++t)
                bfr[t] = mf[((size_t)kt * 16 + t * 4 + quad) * 16 + n];
            float mq = msq[kt * 16 + n];
            floatx4 c = {0.f, 0.f, 0.f, 0.f};
            #pragma unroll
            for (int t = 0; t < 4; ++t)
                c = __builtin_amdgcn_mfma_f32_16x16x32_f16(a[t], bfr[t], c, 0, 0, 0);
            #pragma unroll
            for (int r = 0; r < 4; ++r) {
                float sc = fmaf(-2.f, c[r], mq);    // bit-identical to pass-1 scores
                if (sc >= thr[r]) {
                    int slot = atomicAdd(&cnt[rs[r]], 1);
                    if (slot < CAP) cand[rs[r] * CAP + slot] = kt * 16 + n;
                }
            }
        }
    }
}

// ---- Kernel 5: exact fp32 rescore of candidates. One wave per ambiguous sample.
__global__ __launch_bounds__(256) void rescue_kernel(
        const float* __restrict__ x, const float* __restrict__ mT,
        const float* __restrict__ msq, const int* __restrict__ amb,
        const int* __restrict__ amb_cnt, const int* __restrict__ cnt,
        const int* __restrict__ cand, int* __restrict__ idx_i) {
    const int wv = threadIdx.x >> 6, lane = threadIdx.x & 63;
    const int na = *amb_cnt;
    for (int i = blockIdx.x * 4 + wv; i < na; i += gridDim.x * 4) {
        const int s = amb[i];
        const int c = cnt[s];
        const float2 xx = ((const float2*)x)[(size_t)s * 64 + lane];
        float best = -FLT_MAX; int bk = 0x7fffffff;
        if (c <= CAP) {
            for (int j = 0; j < c; ++j) {
                int k = cand[s * CAP + j];
                float2 mm = ((const float2*)mT)[(size_t)k * 64 + lane];
                float p = xx.x * mm.x + xx.y * mm.y;
                #pragma unroll
                for (int off = 32; off; off >>= 1) p += __shfl_xor(p, off);
                float sc = msq[k] - 2.f * p;        // identical in all lanes
                if (sc > best || (sc == best && k < bk)) { best = sc; bk = k; }
            }
        } else {                // CAP overflow: exact full scan (insurance, ~never)
            for (int k = 0; k < K_CLUST; ++k) {
                float2 mm = ((const float2*)mT)[(size_t)k * 64 + lane];
                float p = xx.x * mm.x + xx.y * mm.y;
                #pragma unroll
                for (int off = 32; off; off >>= 1) p += __shfl_xor(p, off);
                float sc = msq[k] - 2.f * p;
                if (sc > best) { best = sc; bk = k; }
            }
        }
        if (bk == 0x7fffffff) bk = 0;               // safety
        if (lane == 0) idx_i[s] = bk;
    }
}

// ---- Kernel 6: gather quantize (coalesced via mT), write index, MSE.
__global__ void quant_kernel(const float* __restrict__ x, const float* __restrict__ mT,
                             const int* __restrict__ idx_i, float* __restrict__ qout,
                             float* __restrict__ idx_f, float* __restrict__ diff_out) {
    int g = blockIdx.x * 256 + threadIdx.x;     // one thread per (sample, d4)
    int samp = g >> 5;
    int d4   = g & 31;
    int idx  = idx_i[samp];
    float4 q  = ((const float4*)mT)[(size_t)idx * (DIM / 4) + d4];
    float4 xv = ((const float4*)x)[g];
    ((float4*)qout)[g] = q;
    if (d4 == 0) idx_f[samp] = (float)idx;
    float ax = xv.x - q.x, ay = xv.y - q.y, az = xv.z - q.z, aw = xv.w - q.w;
    float dd = ax * ax + ay * ay + az * az + aw * aw;
    #pragma unroll
    for (int off = 32; off; off >>= 1) dd += __shfl_down(dd, off);
    __shared__ float wsum[4];
    int lane = threadIdx.x & 63, wv = threadIdx.x >> 6;
    if (lane == 0) wsum[wv] = dd;
    __syncthreads();
    if (threadIdx.x == 0) {
        float t = wsum[0] + wsum[1] + wsum[2] + wsum[3];
        atomicAdd(diff_out, t * (1.0f / ((float)N_SAMP * (float)DIM)));
    }
}

extern "C" void kernel_launch(void* const* d_in, const int* in_sizes, int n_in,
                              void* d_out, int out_size, void* d_ws, size_t ws_size,
                              hipStream_t stream) {
    const float* x = (const float*)d_in[0];          // [16,32,32,128]
    const float* m = (const float*)d_in[1];          // [128,10000]
    float* out    = (float*)d_out;
    float* quant  = out;                                  // 2,097,152 f
    float* idx_f  = out + (size_t)N_SAMP * DIM;           // 16,384 f
    float* diff   = out + (size_t)N_SAMP * DIM + N_SAMP;  // 1 f

    char* ws = (char*)d_ws;                  // ~16.6 MB total
    float*     msq   = (float*)    (ws);                      // 40,960 B
    float*     mT    = (float*)    (ws + 40960);              // 5,120,000 B
    _Float16*  mh    = (_Float16*) (ws + 5160960);            // 2,621,440 B
    _Float16*  xh    = (_Float16*) (ws + 7782400);            // 4,194,304 B
    u64*       bpack = (u64*)      (ws + 11976704);           // 2,097,152 B
    float*     b2nd  = (float*)    (ws + 14073856);           // 1,048,576 B
    int*       idx_i = (int*)      (ws + 15122432);           // 65,536 B
    int*       amb   = (int*)      (ws + 15187968);           // 65,536 B
    float*     thrb  = (float*)    (ws + 15253504);           // 65,536 B
    int*       cnt   = (int*)      (ws + 15319040);           // 65,536 B
    int*       cand  = (int*)      (ws + 15384576);           // 1,048,576 B
    int*       amb_c = (int*)      (ws + 16433152);           // 4 B

    prep_kernel<<<576, 256, 0, stream>>>(m, x, msq, mT, mh, xh, amb_c, diff);
    score_kernel<<<64 * KSPLIT, 256, 0, stream>>>(xh, mh, msq, bpack, b2nd);
    merge_kernel<<<N_SAMP / 256, 256, 0, stream>>>(bpack, b2nd, idx_i, amb, thrb,
                                                   cnt, amb_c);
    collect_kernel<<<1024, 256, 0, stream>>>(xh, mh, msq, amb, thrb, amb_c, cnt, cand);
    rescue_kernel<<<256, 256, 0, stream>>>(x, mT, msq, amb, amb_c, cnt, cand, idx_i);
    quant_kernel<<<(N_SAMP * DIM / 4) / 256, 256, 0, stream>>>(x, mT, idx_i,
                                                               quant, idx_f, diff);
}